// Round 3
// baseline (211.359 us; speedup 1.0000x reference)
//
#include <hip/hip_runtime.h>
#include <stdint.h>
#include <math.h>

// LabelCls cascade label assignment — dense-threefry 2-phase version.
// Inputs (64, 3*65536) f32; cascade h = cols [h*65536,(h+1)*65536). row = h*64+b.
//
// Phase 1: 3072 blocks (row,seg) x 256 thr, seg = 4096 elems. Pure stream:
//   load ov+iu, write -1 base labels, dense 4-wide threefry (all elements —
//   cheaper than compaction: ~12 us chip-wide VALU vs 24 us memory floor),
//   rare (>0.98) pos/neg candidates pushed to per-(row,seg) global slots.
//   No memset needed: every ctr slot written unconditionally each launch.
// Phase 2: 192 blocks x 1024 thr. Prefix-sum seg counts, gather ~550 cands,
//   exact rank-select (ties == lax.top_k), sparse fixups (pos: -1+2*nm, neg: 0).
//   Slow path = full row recompute on any overflow/deficit (never fires here).
// Fallback: ws too small -> validated mono kernel (round 1).
//
// RNG: JAX threefry2x32 partitionable mode (verified: absmax 0 in R1/R2):
//   keys[h]=TF((0,42),(0,h)); bits=x0^x1 of TF(key_h,(0, b*65536+col));
//   u = bitcast((bits>>9)|0x3f800000)-1.
// Integer threshold: u > 0.98f  <=>  (bits>>9) > 8220836   (0.98f == 8220836*2^-23)

#define NROI 65536
#define ROWSTRIDE (3 * 65536)
#define SEGS 16
#define SEGLEN 4096
#define P1T 256
#define P2T 1024
#define CAP 2048
#define FILT0 0.98f
#define MTHR 8220836u
#define NITER 16  // slow/mono: 65536/4/1024

// ---------------- threefry2x32 (20 rounds) ----------------
#define TF_ROUNDS(x0, x1, R0, R1, R2, R3)                         \
  x0 += x1; x1 = (x1 << R0) | (x1 >> (32 - R0)); x1 ^= x0;        \
  x0 += x1; x1 = (x1 << R1) | (x1 >> (32 - R1)); x1 ^= x0;        \
  x0 += x1; x1 = (x1 << R2) | (x1 >> (32 - R2)); x1 ^= x0;        \
  x0 += x1; x1 = (x1 << R3) | (x1 >> (32 - R3)); x1 ^= x0;

#define TF_BODY(k0, k1, k2, x0, x1)                               \
  TF_ROUNDS(x0, x1, 13, 15, 26, 6)  x0 += k1; x1 += k2 + 1u;      \
  TF_ROUNDS(x0, x1, 17, 29, 16, 24) x0 += k2; x1 += k0 + 2u;      \
  TF_ROUNDS(x0, x1, 13, 15, 26, 6)  x0 += k0; x1 += k1 + 3u;      \
  TF_ROUNDS(x0, x1, 17, 29, 16, 24) x0 += k1; x1 += k2 + 4u;      \
  TF_ROUNDS(x0, x1, 13, 15, 26, 6)  x0 += k2; x1 += k0 + 5u;

__device__ __forceinline__ float tf_uniform(uint32_t k0, uint32_t k1, uint32_t idx) {
  uint32_t k2 = k0 ^ k1 ^ 0x1BD11BDAu;
  uint32_t x0 = 0u + k0;
  uint32_t x1 = idx + k1;
  TF_BODY(k0, k1, k2, x0, x1)
  uint32_t bits = x0 ^ x1;
  return __uint_as_float((bits >> 9) | 0x3f800000u) - 1.0f;
}

// 4 independent threefry chains (ILP-4) for counters cbase..cbase+3.
__device__ __forceinline__ void tf4(uint32_t k0, uint32_t k1, uint32_t cbase,
                                    uint32_t m[4]) {
  uint32_t k2 = k0 ^ k1 ^ 0x1BD11BDAu;
  uint32_t x0[4], x1[4];
#pragma unroll
  for (int i = 0; i < 4; ++i) { x0[i] = k0; x1[i] = cbase + (uint32_t)i + k1; }
#define R4(r)                                                       \
  _Pragma("unroll") for (int i = 0; i < 4; ++i) {                   \
    x0[i] += x1[i];                                                 \
    x1[i] = (x1[i] << (r)) | (x1[i] >> (32 - (r)));                 \
    x1[i] ^= x0[i];                                                 \
  }
#define INJ4(a, bv, ridx)                                           \
  _Pragma("unroll") for (int i = 0; i < 4; ++i) {                   \
    x0[i] += (a); x1[i] += (bv) + (uint32_t)(ridx);                 \
  }
  R4(13) R4(15) R4(26) R4(6)  INJ4(k1, k2, 1)
  R4(17) R4(29) R4(16) R4(24) INJ4(k2, k0, 2)
  R4(13) R4(15) R4(26) R4(6)  INJ4(k0, k1, 3)
  R4(17) R4(29) R4(16) R4(24) INJ4(k1, k2, 4)
  R4(13) R4(15) R4(26) R4(6)  INJ4(k2, k0, 5)
#undef R4
#undef INJ4
#pragma unroll
  for (int i = 0; i < 4; ++i) m[i] = x0[i] ^ x1[i];
}

static void tf_pair_host(uint32_t k0, uint32_t k1, uint32_t c0, uint32_t c1,
                         uint32_t* o0, uint32_t* o1) {
  uint32_t k2 = k0 ^ k1 ^ 0x1BD11BDAu;
  uint32_t x0 = c0 + k0, x1 = c1 + k1;
  TF_BODY(k0, k1, k2, x0, x1)
  *o0 = x0; *o1 = x1;
}

__device__ __forceinline__ void row_consts(int h, uint32_t K00, uint32_t K01,
                                           uint32_t K10, uint32_t K11,
                                           uint32_t K20, uint32_t K21,
                                           float* POS_T, float* IOU_T,
                                           uint32_t* k0, uint32_t* k1) {
  *POS_T = (h == 0) ? 0.6f : ((h == 1) ? 0.7f : 0.8f);
  *IOU_T = (h == 0) ? 0.2f : ((h == 1) ? 0.3f : 0.4f);
  *k0 = (h == 0) ? K00 : ((h == 1) ? K10 : K20);
  *k1 = (h == 0) ? K01 : ((h == 1) ? K11 : K21);
}

// ---------------- Phase 1 ----------------
__global__ __launch_bounds__(P1T) void phase1(
    const float* __restrict__ ov, const float* __restrict__ iu,
    float* __restrict__ out, uint32_t* __restrict__ ctr,
    uint2* __restrict__ posbuf, uint2* __restrict__ negbuf, int SEGCAP,
    uint32_t K00, uint32_t K01, uint32_t K10, uint32_t K11,
    uint32_t K20, uint32_t K21) {
  const int slot = blockIdx.x;
  const int row = slot >> 4;
  const int seg = slot & 15;
  const int h = row >> 6;
  const int b = row & 63;
  const int tid = threadIdx.x;
  float POS_T, IOU_T; uint32_t k0, k1;
  row_consts(h, K00, K01, K10, K11, K20, K21, &POS_T, &IOU_T, &k0, &k1);

  const size_t rowoff = (size_t)b * ROWSTRIDE + (size_t)h * NROI;
  const int segoff = seg * SEGLEN;
  const float4* o4 = (const float4*)(ov + rowoff + segoff);
  const float4* q4 = (const float4*)(iu + rowoff + segoff);
  float4* w4 = (float4*)(out + rowoff + segoff);
  const uint32_t cbase0 = (uint32_t)b * 65536u + (uint32_t)segoff;
  uint2* pb = posbuf + (size_t)slot * SEGCAP;
  uint2* nb = negbuf + (size_t)slot * SEGCAP;

  __shared__ int s_np, s_nn;
  if (tid == 0) { s_np = 0; s_nn = 0; }
  __syncthreads();

  const float4 m1 = make_float4(-1.f, -1.f, -1.f, -1.f);
#pragma unroll 1
  for (int it = 0; it < 4; ++it) {
    int v = it * P1T + tid;
    float4 o = o4[v];
    float4 q = q4[v];
    w4[v] = m1;
    uint32_t m[4];
    tf4(k0, k1, cbase0 + (uint32_t)(4 * v), m);
    int j0 = segoff + 4 * v;  // row-local index
    float oo[4] = {o.x, o.y, o.z, o.w}, qq[4] = {q.x, q.y, q.z, q.w};
#pragma unroll
    for (int c = 0; c < 4; ++c) {
      if (oo[c] >= POS_T && qq[c] > FILT0) {
        int p = atomicAdd(&s_np, 1);
        if (p < SEGCAP) pb[p] = make_uint2(__float_as_uint(qq[c]), (uint32_t)(j0 + c));
      }
      if (oo[c] <= 0.3f && (m[c] >> 9) > MTHR) {
        float u = __uint_as_float((m[c] >> 9) | 0x3f800000u) - 1.0f;
        int p = atomicAdd(&s_nn, 1);
        if (p < SEGCAP) nb[p] = make_uint2(__float_as_uint(u), (uint32_t)(j0 + c));
      }
    }
  }
  __syncthreads();
  if (tid == 0) {
    ctr[slot * 2 + 0] = (uint32_t)s_np;  // raw; phase2 checks > SEGCAP
    ctr[slot * 2 + 1] = (uint32_t)s_nn;
  }
}

// ---------------- Phase 2 ----------------
__global__ __launch_bounds__(P2T) void phase2(
    const float* __restrict__ ov, const float* __restrict__ iu,
    const float* __restrict__ nm, float* __restrict__ out,
    const uint32_t* __restrict__ ctr,
    const uint2* __restrict__ posbuf, const uint2* __restrict__ negbuf, int SEGCAP,
    uint32_t K00, uint32_t K01, uint32_t K10, uint32_t K11,
    uint32_t K20, uint32_t K21) {
  const int row = blockIdx.x;
  const int h = row >> 6;
  const int b = row & 63;
  const int tid = threadIdx.x;
  float POS_T, IOU_T; uint32_t k0, k1;
  row_consts(h, K00, K01, K10, K11, K20, K21, &POS_T, &IOU_T, &k0, &k1);
  const float NEG_T = 0.3f;
  const size_t rowoff = (size_t)b * ROWSTRIDE + (size_t)h * NROI;
  const uint32_t ibase = (uint32_t)b * 65536u;

  __shared__ float ival[CAP];
  __shared__ int   iidx[CAP];
  __shared__ float sval[CAP];
  __shared__ int   sidx[CAP];
  __shared__ uint32_t bitmap[NROI / 32];
  __shared__ int pcnt[SEGS], ncnt[SEGS], pbase[SEGS], nbase[SEGS];
  __shared__ int s_cp, s_cn, s_ok;
  __shared__ int s_nci, s_ncs, s_poscnt;
  __shared__ uint32_t s_maxbits;
  __shared__ float s_kth16, s_top2, s_kth48;

  if (tid < SEGS) {
    pcnt[tid] = (int)ctr[(row * SEGS + tid) * 2 + 0];
    ncnt[tid] = (int)ctr[(row * SEGS + tid) * 2 + 1];
  }
  __syncthreads();
  if (tid == 0) {
    int a = 0, c2 = 0, ok = 1;
    for (int s = 0; s < SEGS; ++s) {
      if (pcnt[s] > SEGCAP || ncnt[s] > SEGCAP) ok = 0;
      pbase[s] = a; a += pcnt[s];
      nbase[s] = c2; c2 += ncnt[s];
    }
    if (a < 16 || a > CAP || c2 < 48 || c2 > CAP) ok = 0;
    s_cp = a; s_cn = c2; s_ok = ok;
  }
  __syncthreads();

  if (s_ok) {
    const int cp = s_cp, cn = s_cn;
    for (int s = 0; s < SEGS; ++s) {
      int n = pcnt[s], bb = pbase[s];
      const uint2* src = posbuf + (size_t)(row * SEGS + s) * SEGCAP;
      for (int i = tid; i < n; i += P2T) {
        uint2 e = src[i];
        ival[bb + i] = __uint_as_float(e.x);
        iidx[bb + i] = (int)e.y;
      }
      n = ncnt[s]; bb = nbase[s];
      const uint2* src2 = negbuf + (size_t)(row * SEGS + s) * SEGCAP;
      for (int i = tid; i < n; i += P2T) {
        uint2 e = src2[i];
        sval[bb + i] = __uint_as_float(e.x);
        sidx[bb + i] = (int)e.y;
      }
    }
    if (tid == 0) { s_kth16 = 0.f; s_top2 = 0.f; s_kth48 = -INFINITY; }
    __syncthreads();
    for (int c = tid; c < cp; c += P2T) {
      float v = ival[c];
      int g = 0, e = 0;
      for (int x = 0; x < cp; ++x) {
        float w = ival[x];
        g += (w > v) ? 1 : 0;
        e += (w == v) ? 1 : 0;
      }
      if (g <= 15 && 15 < g + e) s_kth16 = v;
      if (g <= 1 && 1 < g + e) s_top2 = v;
    }
    for (int c = tid; c < cn; c += P2T) {
      float v = sval[c];
      int g = 0, e = 0;
      for (int x = 0; x < cn; ++x) {
        float w = sval[x];
        g += (w > v) ? 1 : 0;
        e += (w == v) ? 1 : 0;
      }
      if (g <= 47 && 47 < g + e) s_kth48 = v;
    }
    __syncthreads();
    const float t = (s_kth16 >= IOU_T) ? s_kth16 : IOU_T;  // cp>=16 -> kth16>0.98
    const float top2 = s_top2;
    const float kth48 = s_kth48;
    for (int c = tid; c < cp; c += P2T) {
      float v = ival[c];
      bool pos = (v >= t) || (h == 0 && v > top2);
      if (pos) {
        size_t gi = rowoff + (size_t)iidx[c];
        out[gi] = -1.f + 2.f * nm[gi];  // neg impossible here (ov>=POS_T>0.3)
      }
    }
    for (int c = tid; c < cn; c += P2T) {
      if (sval[c] >= kth48) out[rowoff + (size_t)sidx[c]] = 0.f;  // -1 + 1
    }
    return;
  }

  // ---------- slow path: full row recompute (validated round-1 logic) ----------
  const float4* ov4 = (const float4*)(ov + rowoff);
  const float4* iu4 = (const float4*)(iu + rowoff);
  float4* out4 = (float4*)(out + rowoff);

  if (tid == 0) { s_nci = 0; s_ncs = 0; s_poscnt = 0; s_maxbits = 0u; }
  for (int w = tid; w < NROI / 32; w += P2T) bitmap[w] = 0u;
  __syncthreads();

  int poscnt_l = 0;
  uint32_t maxb_l = 0u;
#pragma unroll 1
  for (int it = 0; it < NITER; ++it) {
    int v4i = it * P2T + tid;
    float4 o = ov4[v4i];
    float4 q = iu4[v4i];
    int j0 = v4i * 4;
    float ov_[4] = {o.x, o.y, o.z, o.w};
    float iu_[4] = {q.x, q.y, q.z, q.w};
#pragma unroll
    for (int c = 0; c < 4; ++c) {
      float ovv = ov_[c], iuv = iu_[c];
      int j = j0 + c;
      bool pos = ovv >= POS_T;
      poscnt_l += pos ? 1 : 0;
      uint32_t ib = __float_as_uint(iuv);
      maxb_l = ib > maxb_l ? ib : maxb_l;
      if (pos && iuv > FILT0) {
        int p = atomicAdd(&s_nci, 1);
        if (p < CAP) { ival[p] = iuv; iidx[p] = j; }
      }
      if (ovv <= NEG_T) {
        float u = tf_uniform(k0, k1, ibase + (uint32_t)j);
        if (u > FILT0) {
          int p = atomicAdd(&s_ncs, 1);
          if (p < CAP) { sval[p] = u; sidx[p] = j; }
        }
      }
    }
  }
  atomicAdd(&s_poscnt, poscnt_l);
  atomicMax(&s_maxbits, maxb_l);
  __syncthreads();

  int nci = min(s_nci, CAP);
  int ncs = min(s_ncs, CAP);
  const int pos_cnt = s_poscnt;
  const float max_iou = __uint_as_float(s_maxbits);

  float kth16 = 0.f, top2 = 0.f;

  if (pos_cnt == 0) {
    if (tid == 0) s_nci = 0;
    __syncthreads();
#pragma unroll 1
    for (int it = 0; it < NITER; ++it) {
      int v4i = it * P2T + tid;
      float4 q = iu4[v4i];
      int j0 = v4i * 4;
      float iu_[4] = {q.x, q.y, q.z, q.w};
#pragma unroll
      for (int c = 0; c < 4; ++c) {
        if (__float_as_uint(iu_[c]) == s_maxbits) {
          int p = atomicAdd(&s_nci, 1);
          if (p < CAP) { ival[p] = iu_[c]; iidx[p] = j0 + c; }
        }
      }
    }
    __syncthreads();
    int cmax = s_nci;
    nci = min(cmax, CAP);
    kth16 = (cmax >= 16) ? max_iou : 0.f;
    top2 = (cmax >= 2) ? max_iou : 0.f;
  } else {
    float lo = FILT0;
    while (nci < 16 && nci < pos_cnt && lo > 0.f) {
      float hi = lo;
      lo = fmaxf(0.f, 1.f - 2.f * (1.f - lo));
      __syncthreads();
#pragma unroll 1
      for (int it = 0; it < NITER; ++it) {
        int v4i = it * P2T + tid;
        float4 o = ov4[v4i];
        float4 q = iu4[v4i];
        int j0 = v4i * 4;
        float ov_[4] = {o.x, o.y, o.z, o.w};
        float iu_[4] = {q.x, q.y, q.z, q.w};
#pragma unroll
        for (int c = 0; c < 4; ++c) {
          if (ov_[c] >= POS_T && iu_[c] > lo && iu_[c] <= hi) {
            int p = atomicAdd(&s_nci, 1);
            if (p < CAP) { ival[p] = iu_[c]; iidx[p] = j0 + c; }
          }
        }
      }
      __syncthreads();
      nci = min(s_nci, CAP);
    }
    if (tid == 0) { s_kth16 = 0.f; s_top2 = 0.f; }
    __syncthreads();
    for (int c = tid; c < nci; c += P2T) {
      float v = ival[c];
      int g = 0, e = 0;
      for (int x = 0; x < nci; ++x) {
        float w = ival[x];
        g += (w > v) ? 1 : 0;
        e += (w == v) ? 1 : 0;
      }
      if (g <= 15 && 15 < g + e) s_kth16 = v;
      if (g <= 1 && 1 < g + e) s_top2 = v;
    }
    __syncthreads();
    kth16 = s_kth16;
    top2 = s_top2;
  }
  const float t = (kth16 >= IOU_T) ? kth16 : IOU_T;

  {
    float lo = FILT0;
    while (ncs < 48 && lo > 0.f) {
      float hi = lo;
      lo = fmaxf(0.f, 1.f - 2.f * (1.f - lo));
      __syncthreads();
#pragma unroll 1
      for (int it = 0; it < NITER; ++it) {
        int v4i = it * P2T + tid;
        float4 o = ov4[v4i];
        int j0 = v4i * 4;
        float ov_[4] = {o.x, o.y, o.z, o.w};
#pragma unroll
        for (int c = 0; c < 4; ++c) {
          if (ov_[c] <= NEG_T) {
            float u = tf_uniform(k0, k1, ibase + (uint32_t)(j0 + c));
            if (u > lo && u <= hi) {
              int p = atomicAdd(&s_ncs, 1);
              if (p < CAP) { sval[p] = u; sidx[p] = j0 + c; }
            }
          }
        }
      }
      __syncthreads();
      ncs = min(s_ncs, CAP);
    }
  }
  if (tid == 0) s_kth48 = -INFINITY;
  __syncthreads();
  for (int c = tid; c < ncs; c += P2T) {
    float v = sval[c];
    int g = 0, e = 0;
    for (int x = 0; x < ncs; ++x) {
      float w = sval[x];
      g += (w > v) ? 1 : 0;
      e += (w == v) ? 1 : 0;
    }
    if (g <= 47 && 47 < g + e) s_kth48 = v;
  }
  __syncthreads();
  const float kth48 = s_kth48;
  for (int c = tid; c < ncs; c += P2T) {
    if (sval[c] >= kth48) atomicOr(&bitmap[sidx[c] >> 5], 1u << (sidx[c] & 31));
  }
  __syncthreads();

#pragma unroll 1
  for (int it = 0; it < NITER; ++it) {
    int v4i = it * P2T + tid;
    int j0 = v4i * 4;
    uint32_t w = bitmap[j0 >> 5];
    uint32_t sh = (uint32_t)(j0 & 31);
    float4 r;
    r.x = -1.f + (float)((w >> (sh + 0)) & 1u);
    r.y = -1.f + (float)((w >> (sh + 1)) & 1u);
    r.z = -1.f + (float)((w >> (sh + 2)) & 1u);
    r.w = -1.f + (float)((w >> (sh + 3)) & 1u);
    out4[v4i] = r;
  }
  __syncthreads();

  for (int c = tid; c < nci; c += P2T) {
    float v = ival[c];
    bool pos = (v >= t) || (h == 0 && v > top2);
    if (pos) {
      size_t gi = rowoff + (size_t)iidx[c];
      float nmv = nm[gi];
      if (nmv != 0.f) atomicAdd(&out[gi], 2.f * nmv);
    }
  }
}

// ---------------- mono fallback (round-1 kernel, validated) ----------------
__global__ __launch_bounds__(P2T) void label_kernel_mono(
    const float* __restrict__ ov, const float* __restrict__ iu,
    const float* __restrict__ nm, float* __restrict__ out,
    uint32_t K00, uint32_t K01, uint32_t K10, uint32_t K11,
    uint32_t K20, uint32_t K21) {
  const int bid = blockIdx.x;
  const int h = bid >> 6;
  const int b = bid & 63;
  const int tid = threadIdx.x;
  float POS_T, IOU_T; uint32_t k0, k1;
  row_consts(h, K00, K01, K10, K11, K20, K21, &POS_T, &IOU_T, &k0, &k1);
  const float NEG_T = 0.3f;
  const size_t rowoff = (size_t)b * ROWSTRIDE + (size_t)h * NROI;
  const float4* ov4 = (const float4*)(ov + rowoff);
  const float4* iu4 = (const float4*)(iu + rowoff);
  float4* out4 = (float4*)(out + rowoff);
  const uint32_t ibase = (uint32_t)b * (uint32_t)NROI;

  __shared__ float ival[CAP];
  __shared__ int   iidx[CAP];
  __shared__ float sval[CAP];
  __shared__ int   sidx[CAP];
  __shared__ uint32_t bitmap[NROI / 32];
  __shared__ int s_nci, s_ncs, s_poscnt;
  __shared__ uint32_t s_maxbits;
  __shared__ float s_kth16, s_top2, s_kth48;

  if (tid == 0) { s_nci = 0; s_ncs = 0; s_poscnt = 0; s_maxbits = 0u; }
  for (int w = tid; w < NROI / 32; w += P2T) bitmap[w] = 0u;
  __syncthreads();

  int poscnt_l = 0;
  uint32_t maxb_l = 0u;
#pragma unroll 1
  for (int it = 0; it < NITER; ++it) {
    int v4i = it * P2T + tid;
    float4 o = ov4[v4i];
    float4 q = iu4[v4i];
    int j0 = v4i * 4;
    float ov_[4] = {o.x, o.y, o.z, o.w};
    float iu_[4] = {q.x, q.y, q.z, q.w};
#pragma unroll
    for (int c = 0; c < 4; ++c) {
      float ovv = ov_[c], iuv = iu_[c];
      int j = j0 + c;
      bool pos = ovv >= POS_T;
      poscnt_l += pos ? 1 : 0;
      uint32_t ib = __float_as_uint(iuv);
      maxb_l = ib > maxb_l ? ib : maxb_l;
      if (pos && iuv > FILT0) {
        int p = atomicAdd(&s_nci, 1);
        if (p < CAP) { ival[p] = iuv; iidx[p] = j; }
      }
      if (ovv <= NEG_T) {
        float u = tf_uniform(k0, k1, ibase + (uint32_t)j);
        if (u > FILT0) {
          int p = atomicAdd(&s_ncs, 1);
          if (p < CAP) { sval[p] = u; sidx[p] = j; }
        }
      }
    }
  }
  atomicAdd(&s_poscnt, poscnt_l);
  atomicMax(&s_maxbits, maxb_l);
  __syncthreads();

  int nci = min(s_nci, CAP);
  int ncs = min(s_ncs, CAP);
  const int pos_cnt = s_poscnt;
  const float max_iou = __uint_as_float(s_maxbits);

  float kth16 = 0.f, top2 = 0.f;

  if (pos_cnt == 0) {
    if (tid == 0) s_nci = 0;
    __syncthreads();
#pragma unroll 1
    for (int it = 0; it < NITER; ++it) {
      int v4i = it * P2T + tid;
      float4 q = iu4[v4i];
      int j0 = v4i * 4;
      float iu_[4] = {q.x, q.y, q.z, q.w};
#pragma unroll
      for (int c = 0; c < 4; ++c) {
        if (__float_as_uint(iu_[c]) == s_maxbits) {
          int p = atomicAdd(&s_nci, 1);
          if (p < CAP) { ival[p] = iu_[c]; iidx[p] = j0 + c; }
        }
      }
    }
    __syncthreads();
    int cmax = s_nci;
    nci = min(cmax, CAP);
    kth16 = (cmax >= 16) ? max_iou : 0.f;
    top2 = (cmax >= 2) ? max_iou : 0.f;
  } else {
    float lo = FILT0;
    while (nci < 16 && nci < pos_cnt && lo > 0.f) {
      float hi = lo;
      lo = fmaxf(0.f, 1.f - 2.f * (1.f - lo));
      __syncthreads();
#pragma unroll 1
      for (int it = 0; it < NITER; ++it) {
        int v4i = it * P2T + tid;
        float4 o = ov4[v4i];
        float4 q = iu4[v4i];
        int j0 = v4i * 4;
        float ov_[4] = {o.x, o.y, o.z, o.w};
        float iu_[4] = {q.x, q.y, q.z, q.w};
#pragma unroll
        for (int c = 0; c < 4; ++c) {
          if (ov_[c] >= POS_T && iu_[c] > lo && iu_[c] <= hi) {
            int p = atomicAdd(&s_nci, 1);
            if (p < CAP) { ival[p] = iu_[c]; iidx[p] = j0 + c; }
          }
        }
      }
      __syncthreads();
      nci = min(s_nci, CAP);
    }
    if (tid == 0) { s_kth16 = 0.f; s_top2 = 0.f; }
    __syncthreads();
    for (int c = tid; c < nci; c += P2T) {
      float v = ival[c];
      int g = 0, e = 0;
      for (int x = 0; x < nci; ++x) {
        float w = ival[x];
        g += (w > v) ? 1 : 0;
        e += (w == v) ? 1 : 0;
      }
      if (g <= 15 && 15 < g + e) s_kth16 = v;
      if (g <= 1 && 1 < g + e) s_top2 = v;
    }
    __syncthreads();
    kth16 = s_kth16;
    top2 = s_top2;
  }
  const float t = (kth16 >= IOU_T) ? kth16 : IOU_T;

  {
    float lo = FILT0;
    while (ncs < 48 && lo > 0.f) {
      float hi = lo;
      lo = fmaxf(0.f, 1.f - 2.f * (1.f - lo));
      __syncthreads();
#pragma unroll 1
      for (int it = 0; it < NITER; ++it) {
        int v4i = it * P2T + tid;
        float4 o = ov4[v4i];
        int j0 = v4i * 4;
        float ov_[4] = {o.x, o.y, o.z, o.w};
#pragma unroll
        for (int c = 0; c < 4; ++c) {
          if (ov_[c] <= NEG_T) {
            float u = tf_uniform(k0, k1, ibase + (uint32_t)(j0 + c));
            if (u > lo && u <= hi) {
              int p = atomicAdd(&s_ncs, 1);
              if (p < CAP) { sval[p] = u; sidx[p] = j0 + c; }
            }
          }
        }
      }
      __syncthreads();
      ncs = min(s_ncs, CAP);
    }
  }
  if (tid == 0) s_kth48 = -INFINITY;
  __syncthreads();
  for (int c = tid; c < ncs; c += P2T) {
    float v = sval[c];
    int g = 0, e = 0;
    for (int x = 0; x < ncs; ++x) {
      float w = sval[x];
      g += (w > v) ? 1 : 0;
      e += (w == v) ? 1 : 0;
    }
    if (g <= 47 && 47 < g + e) s_kth48 = v;
  }
  __syncthreads();
  const float kth48 = s_kth48;
  for (int c = tid; c < ncs; c += P2T) {
    if (sval[c] >= kth48) atomicOr(&bitmap[sidx[c] >> 5], 1u << (sidx[c] & 31));
  }
  __syncthreads();

#pragma unroll 1
  for (int it = 0; it < NITER; ++it) {
    int v4i = it * P2T + tid;
    int j0 = v4i * 4;
    uint32_t w = bitmap[j0 >> 5];
    uint32_t sh = (uint32_t)(j0 & 31);
    float4 r;
    r.x = -1.f + (float)((w >> (sh + 0)) & 1u);
    r.y = -1.f + (float)((w >> (sh + 1)) & 1u);
    r.z = -1.f + (float)((w >> (sh + 2)) & 1u);
    r.w = -1.f + (float)((w >> (sh + 3)) & 1u);
    out4[v4i] = r;
  }
  __syncthreads();

  for (int c = tid; c < nci; c += P2T) {
    float v = ival[c];
    bool pos = (v >= t) || (h == 0 && v > top2);
    if (pos) {
      size_t gi = rowoff + (size_t)iidx[c];
      float nmv = nm[gi];
      if (nmv != 0.f) atomicAdd(&out[gi], 2.f * nmv);
    }
  }
}

extern "C" void kernel_launch(void* const* d_in, const int* in_sizes, int n_in,
                              void* d_out, int out_size, void* d_ws, size_t ws_size,
                              hipStream_t stream) {
  const float* ov = (const float*)d_in[0];
  const float* iu = (const float*)d_in[1];
  const float* nm = (const float*)d_in[2];
  float* out = (float*)d_out;

  uint32_t ka[3], kb[3];
  for (uint32_t h = 0; h < 3; ++h) tf_pair_host(0u, 42u, 0u, h, &ka[h], &kb[h]);

  const int nslots = 192 * SEGS;  // 3072
  const size_t ctr_bytes = (size_t)nslots * 2 * sizeof(uint32_t);  // 24576, 8B-aligned
  int SEGCAP = 128;  // mean ~33/seg, Poisson: overflow prob ~1e-30; slow path covers
  size_t need = ctr_bytes + 2ull * nslots * SEGCAP * sizeof(uint2);
  if (ws_size < need) {
    SEGCAP = (ws_size > ctr_bytes)
                 ? (int)((ws_size - ctr_bytes) / (2ull * nslots * sizeof(uint2)))
                 : 0;
  }

  if (SEGCAP >= 64) {
    uint32_t* ctr = (uint32_t*)d_ws;
    uint2* posbuf = (uint2*)((char*)d_ws + ctr_bytes);
    uint2* negbuf = posbuf + (size_t)nslots * SEGCAP;
    hipLaunchKernelGGL(phase1, dim3(nslots), dim3(P1T), 0, stream,
                       ov, iu, out, ctr, posbuf, negbuf, SEGCAP,
                       ka[0], kb[0], ka[1], kb[1], ka[2], kb[2]);
    hipLaunchKernelGGL(phase2, dim3(192), dim3(P2T), 0, stream,
                       ov, iu, nm, out, ctr, posbuf, negbuf, SEGCAP,
                       ka[0], kb[0], ka[1], kb[1], ka[2], kb[2]);
  } else {
    hipLaunchKernelGGL(label_kernel_mono, dim3(192), dim3(P2T), 0, stream,
                       ov, iu, nm, out, ka[0], kb[0], ka[1], kb[1], ka[2], kb[2]);
  }
}

// Round 5
// 201.231 us; speedup vs baseline: 1.0503x; 1.0503x over previous
//
#include <hip/hip_runtime.h>
#include <stdint.h>
#include <math.h>

// LabelCls cascade label assignment — dense-threefry 2-phase version (R5 = R4 fixed).
// Inputs (64, 3*65536) f32; cascade h = cols [h*65536,(h+1)*65536). row = h*64+b.
//
// R4/R5 changes vs R3 (phase1 @58us, VALUBusy 50%, Occupancy 52%):
//  - SEGS 16->8: grid 1536 = 6 blocks/CU (24 waves) -> single uniform residency
//    round (R3's 3072 = 12/CU vs 8-resident cap gave a half-occupancy tail).
//  - unroll 2 (was unroll 1): lets loads of iter i+1 overlap tf4 of iter i.
//  - nontemporal loads/stores on the streaming path via ext_vector_type(4)
//    (R4 failed: builtin rejects HIP_vector_type wrapper).
// Phase 2 (192 blocks x 1024): prefix seg counts, gather ~500-900 cands, exact
// rank-select (ties == lax.top_k), sparse fixups (pos: -1+2*nm, neg: 0).
// Slow path = full row recompute on overflow/deficit. Mono fallback if ws tiny.
//
// RNG: JAX threefry2x32 partitionable mode (verified absmax 0, R1-R3):
//   keys[h]=TF((0,42),(0,h)); bits=x0^x1 of TF(key_h,(0, b*65536+col));
//   u = bitcast((bits>>9)|0x3f800000)-1.   u>0.98f <=> (bits>>9)>8220836.

#define NROI 65536
#define ROWSTRIDE (3 * 65536)
#define SEGS 8
#define SEGLEN 8192
#define P1T 256
#define P1ITER 8   // SEGLEN/4/P1T
#define P2T 1024
#define CAP 2048
#define FILT0 0.98f
#define MTHR 8220836u
#define NITER 16  // slow/mono: 65536/4/1024

typedef float fvec4 __attribute__((ext_vector_type(4)));

// ---------------- threefry2x32 (20 rounds) ----------------
#define TF_ROUNDS(x0, x1, R0, R1, R2, R3)                         \
  x0 += x1; x1 = (x1 << R0) | (x1 >> (32 - R0)); x1 ^= x0;        \
  x0 += x1; x1 = (x1 << R1) | (x1 >> (32 - R1)); x1 ^= x0;        \
  x0 += x1; x1 = (x1 << R2) | (x1 >> (32 - R2)); x1 ^= x0;        \
  x0 += x1; x1 = (x1 << R3) | (x1 >> (32 - R3)); x1 ^= x0;

#define TF_BODY(k0, k1, k2, x0, x1)                               \
  TF_ROUNDS(x0, x1, 13, 15, 26, 6)  x0 += k1; x1 += k2 + 1u;      \
  TF_ROUNDS(x0, x1, 17, 29, 16, 24) x0 += k2; x1 += k0 + 2u;      \
  TF_ROUNDS(x0, x1, 13, 15, 26, 6)  x0 += k0; x1 += k1 + 3u;      \
  TF_ROUNDS(x0, x1, 17, 29, 16, 24) x0 += k1; x1 += k2 + 4u;      \
  TF_ROUNDS(x0, x1, 13, 15, 26, 6)  x0 += k2; x1 += k0 + 5u;

__device__ __forceinline__ float tf_uniform(uint32_t k0, uint32_t k1, uint32_t idx) {
  uint32_t k2 = k0 ^ k1 ^ 0x1BD11BDAu;
  uint32_t x0 = 0u + k0;
  uint32_t x1 = idx + k1;
  TF_BODY(k0, k1, k2, x0, x1)
  uint32_t bits = x0 ^ x1;
  return __uint_as_float((bits >> 9) | 0x3f800000u) - 1.0f;
}

// 4 independent threefry chains (ILP-4) for counters cbase..cbase+3.
__device__ __forceinline__ void tf4(uint32_t k0, uint32_t k1, uint32_t cbase,
                                    uint32_t m[4]) {
  uint32_t k2 = k0 ^ k1 ^ 0x1BD11BDAu;
  uint32_t x0[4], x1[4];
#pragma unroll
  for (int i = 0; i < 4; ++i) { x0[i] = k0; x1[i] = cbase + (uint32_t)i + k1; }
#define R4(r)                                                       \
  _Pragma("unroll") for (int i = 0; i < 4; ++i) {                   \
    x0[i] += x1[i];                                                 \
    x1[i] = (x1[i] << (r)) | (x1[i] >> (32 - (r)));                 \
    x1[i] ^= x0[i];                                                 \
  }
#define INJ4(a, bv, ridx)                                           \
  _Pragma("unroll") for (int i = 0; i < 4; ++i) {                   \
    x0[i] += (a); x1[i] += (bv) + (uint32_t)(ridx);                 \
  }
  R4(13) R4(15) R4(26) R4(6)  INJ4(k1, k2, 1)
  R4(17) R4(29) R4(16) R4(24) INJ4(k2, k0, 2)
  R4(13) R4(15) R4(26) R4(6)  INJ4(k0, k1, 3)
  R4(17) R4(29) R4(16) R4(24) INJ4(k1, k2, 4)
  R4(13) R4(15) R4(26) R4(6)  INJ4(k2, k0, 5)
#undef R4
#undef INJ4
#pragma unroll
  for (int i = 0; i < 4; ++i) m[i] = x0[i] ^ x1[i];
}

static void tf_pair_host(uint32_t k0, uint32_t k1, uint32_t c0, uint32_t c1,
                         uint32_t* o0, uint32_t* o1) {
  uint32_t k2 = k0 ^ k1 ^ 0x1BD11BDAu;
  uint32_t x0 = c0 + k0, x1 = c1 + k1;
  TF_BODY(k0, k1, k2, x0, x1)
  *o0 = x0; *o1 = x1;
}

__device__ __forceinline__ void row_consts(int h, uint32_t K00, uint32_t K01,
                                           uint32_t K10, uint32_t K11,
                                           uint32_t K20, uint32_t K21,
                                           float* POS_T, float* IOU_T,
                                           uint32_t* k0, uint32_t* k1) {
  *POS_T = (h == 0) ? 0.6f : ((h == 1) ? 0.7f : 0.8f);
  *IOU_T = (h == 0) ? 0.2f : ((h == 1) ? 0.3f : 0.4f);
  *k0 = (h == 0) ? K00 : ((h == 1) ? K10 : K20);
  *k1 = (h == 0) ? K01 : ((h == 1) ? K11 : K21);
}

// ---------------- Phase 1 ----------------
// __launch_bounds__(256, 6): 6 waves/SIMD -> 6 blocks/CU -> 1536 blocks fill
// 256 CUs in exactly one residency round; caps VGPR at ~85 (plenty).
__global__ __launch_bounds__(P1T, 6) void phase1(
    const float* __restrict__ ov, const float* __restrict__ iu,
    float* __restrict__ out, uint32_t* __restrict__ ctr,
    uint2* __restrict__ posbuf, uint2* __restrict__ negbuf, int SEGCAP,
    uint32_t K00, uint32_t K01, uint32_t K10, uint32_t K11,
    uint32_t K20, uint32_t K21) {
  const int slot = blockIdx.x;
  const int row = slot >> 3;  // SEGS = 8
  const int seg = slot & 7;
  const int h = row >> 6;
  const int b = row & 63;
  const int tid = threadIdx.x;
  float POS_T, IOU_T; uint32_t k0, k1;
  row_consts(h, K00, K01, K10, K11, K20, K21, &POS_T, &IOU_T, &k0, &k1);

  const size_t rowoff = (size_t)b * ROWSTRIDE + (size_t)h * NROI;
  const int segoff = seg * SEGLEN;
  const fvec4* o4 = (const fvec4*)(ov + rowoff + segoff);
  const fvec4* q4 = (const fvec4*)(iu + rowoff + segoff);
  fvec4* w4 = (fvec4*)(out + rowoff + segoff);
  const uint32_t cbase0 = (uint32_t)b * 65536u + (uint32_t)segoff;
  uint2* pb = posbuf + (size_t)slot * SEGCAP;
  uint2* nb = negbuf + (size_t)slot * SEGCAP;

  __shared__ int s_np, s_nn;
  if (tid == 0) { s_np = 0; s_nn = 0; }
  __syncthreads();

  const fvec4 m1 = {-1.f, -1.f, -1.f, -1.f};
#pragma unroll 2
  for (int it = 0; it < P1ITER; ++it) {
    int v = it * P1T + tid;
    fvec4 o = __builtin_nontemporal_load(&o4[v]);
    fvec4 q = __builtin_nontemporal_load(&q4[v]);
    __builtin_nontemporal_store(m1, &w4[v]);
    uint32_t m[4];
    tf4(k0, k1, cbase0 + (uint32_t)(4 * v), m);
    int j0 = segoff + 4 * v;  // row-local index
#pragma unroll
    for (int c = 0; c < 4; ++c) {
      float ovv = o[c], iuv = q[c];
      if (ovv >= POS_T && iuv > FILT0) {
        int p = atomicAdd(&s_np, 1);
        if (p < SEGCAP) pb[p] = make_uint2(__float_as_uint(iuv), (uint32_t)(j0 + c));
      }
      if (ovv <= 0.3f && (m[c] >> 9) > MTHR) {
        float u = __uint_as_float((m[c] >> 9) | 0x3f800000u) - 1.0f;
        int p = atomicAdd(&s_nn, 1);
        if (p < SEGCAP) nb[p] = make_uint2(__float_as_uint(u), (uint32_t)(j0 + c));
      }
    }
  }
  __syncthreads();
  if (tid == 0) {
    ctr[slot * 2 + 0] = (uint32_t)s_np;  // raw; phase2 checks > SEGCAP
    ctr[slot * 2 + 1] = (uint32_t)s_nn;
  }
}

// ---------------- Phase 2 ----------------
__global__ __launch_bounds__(P2T) void phase2(
    const float* __restrict__ ov, const float* __restrict__ iu,
    const float* __restrict__ nm, float* __restrict__ out,
    const uint32_t* __restrict__ ctr,
    const uint2* __restrict__ posbuf, const uint2* __restrict__ negbuf, int SEGCAP,
    uint32_t K00, uint32_t K01, uint32_t K10, uint32_t K11,
    uint32_t K20, uint32_t K21) {
  const int row = blockIdx.x;
  const int h = row >> 6;
  const int b = row & 63;
  const int tid = threadIdx.x;
  float POS_T, IOU_T; uint32_t k0, k1;
  row_consts(h, K00, K01, K10, K11, K20, K21, &POS_T, &IOU_T, &k0, &k1);
  const float NEG_T = 0.3f;
  const size_t rowoff = (size_t)b * ROWSTRIDE + (size_t)h * NROI;
  const uint32_t ibase = (uint32_t)b * 65536u;

  __shared__ float ival[CAP];
  __shared__ int   iidx[CAP];
  __shared__ float sval[CAP];
  __shared__ int   sidx[CAP];
  __shared__ uint32_t bitmap[NROI / 32];
  __shared__ int pcnt[SEGS], ncnt[SEGS], pbase[SEGS], nbase[SEGS];
  __shared__ int s_cp, s_cn, s_ok;
  __shared__ int s_nci, s_ncs, s_poscnt;
  __shared__ uint32_t s_maxbits;
  __shared__ float s_kth16, s_top2, s_kth48;

  if (tid < SEGS) {
    pcnt[tid] = (int)ctr[(row * SEGS + tid) * 2 + 0];
    ncnt[tid] = (int)ctr[(row * SEGS + tid) * 2 + 1];
  }
  __syncthreads();
  if (tid == 0) {
    int a = 0, c2 = 0, ok = 1;
    for (int s = 0; s < SEGS; ++s) {
      if (pcnt[s] > SEGCAP || ncnt[s] > SEGCAP) ok = 0;
      pbase[s] = a; a += pcnt[s];
      nbase[s] = c2; c2 += ncnt[s];
    }
    if (a < 16 || a > CAP || c2 < 48 || c2 > CAP) ok = 0;
    s_cp = a; s_cn = c2; s_ok = ok;
  }
  __syncthreads();

  if (s_ok) {
    const int cp = s_cp, cn = s_cn;
    for (int s = 0; s < SEGS; ++s) {
      int n = pcnt[s], bb = pbase[s];
      const uint2* src = posbuf + (size_t)(row * SEGS + s) * SEGCAP;
      for (int i = tid; i < n; i += P2T) {
        uint2 e = src[i];
        ival[bb + i] = __uint_as_float(e.x);
        iidx[bb + i] = (int)e.y;
      }
      n = ncnt[s]; bb = nbase[s];
      const uint2* src2 = negbuf + (size_t)(row * SEGS + s) * SEGCAP;
      for (int i = tid; i < n; i += P2T) {
        uint2 e = src2[i];
        sval[bb + i] = __uint_as_float(e.x);
        sidx[bb + i] = (int)e.y;
      }
    }
    if (tid == 0) { s_kth16 = 0.f; s_top2 = 0.f; s_kth48 = -INFINITY; }
    __syncthreads();
    for (int c = tid; c < cp; c += P2T) {
      float v = ival[c];
      int g = 0, e = 0;
      for (int x = 0; x < cp; ++x) {
        float w = ival[x];
        g += (w > v) ? 1 : 0;
        e += (w == v) ? 1 : 0;
      }
      if (g <= 15 && 15 < g + e) s_kth16 = v;
      if (g <= 1 && 1 < g + e) s_top2 = v;
    }
    for (int c = tid; c < cn; c += P2T) {
      float v = sval[c];
      int g = 0, e = 0;
      for (int x = 0; x < cn; ++x) {
        float w = sval[x];
        g += (w > v) ? 1 : 0;
        e += (w == v) ? 1 : 0;
      }
      if (g <= 47 && 47 < g + e) s_kth48 = v;
    }
    __syncthreads();
    const float t = (s_kth16 >= IOU_T) ? s_kth16 : IOU_T;  // cp>=16 -> kth16>0.98
    const float top2 = s_top2;
    const float kth48 = s_kth48;
    for (int c = tid; c < cp; c += P2T) {
      float v = ival[c];
      bool pos = (v >= t) || (h == 0 && v > top2);
      if (pos) {
        size_t gi = rowoff + (size_t)iidx[c];
        out[gi] = -1.f + 2.f * nm[gi];  // neg impossible here (ov>=POS_T>0.3)
      }
    }
    for (int c = tid; c < cn; c += P2T) {
      if (sval[c] >= kth48) out[rowoff + (size_t)sidx[c]] = 0.f;  // -1 + 1
    }
    return;
  }

  // ---------- slow path: full row recompute (validated round-1 logic) ----------
  const float4* ov4 = (const float4*)(ov + rowoff);
  const float4* iu4 = (const float4*)(iu + rowoff);
  float4* out4 = (float4*)(out + rowoff);

  if (tid == 0) { s_nci = 0; s_ncs = 0; s_poscnt = 0; s_maxbits = 0u; }
  for (int w = tid; w < NROI / 32; w += P2T) bitmap[w] = 0u;
  __syncthreads();

  int poscnt_l = 0;
  uint32_t maxb_l = 0u;
#pragma unroll 1
  for (int it = 0; it < NITER; ++it) {
    int v4i = it * P2T + tid;
    float4 o = ov4[v4i];
    float4 q = iu4[v4i];
    int j0 = v4i * 4;
    float ov_[4] = {o.x, o.y, o.z, o.w};
    float iu_[4] = {q.x, q.y, q.z, q.w};
#pragma unroll
    for (int c = 0; c < 4; ++c) {
      float ovv = ov_[c], iuv = iu_[c];
      int j = j0 + c;
      bool pos = ovv >= POS_T;
      poscnt_l += pos ? 1 : 0;
      uint32_t ib = __float_as_uint(iuv);
      maxb_l = ib > maxb_l ? ib : maxb_l;
      if (pos && iuv > FILT0) {
        int p = atomicAdd(&s_nci, 1);
        if (p < CAP) { ival[p] = iuv; iidx[p] = j; }
      }
      if (ovv <= NEG_T) {
        float u = tf_uniform(k0, k1, ibase + (uint32_t)j);
        if (u > FILT0) {
          int p = atomicAdd(&s_ncs, 1);
          if (p < CAP) { sval[p] = u; sidx[p] = j; }
        }
      }
    }
  }
  atomicAdd(&s_poscnt, poscnt_l);
  atomicMax(&s_maxbits, maxb_l);
  __syncthreads();

  int nci = min(s_nci, CAP);
  int ncs = min(s_ncs, CAP);
  const int pos_cnt = s_poscnt;
  const float max_iou = __uint_as_float(s_maxbits);

  float kth16 = 0.f, top2 = 0.f;

  if (pos_cnt == 0) {
    if (tid == 0) s_nci = 0;
    __syncthreads();
#pragma unroll 1
    for (int it = 0; it < NITER; ++it) {
      int v4i = it * P2T + tid;
      float4 q = iu4[v4i];
      int j0 = v4i * 4;
      float iu_[4] = {q.x, q.y, q.z, q.w};
#pragma unroll
      for (int c = 0; c < 4; ++c) {
        if (__float_as_uint(iu_[c]) == s_maxbits) {
          int p = atomicAdd(&s_nci, 1);
          if (p < CAP) { ival[p] = iu_[c]; iidx[p] = j0 + c; }
        }
      }
    }
    __syncthreads();
    int cmax = s_nci;
    nci = min(cmax, CAP);
    kth16 = (cmax >= 16) ? max_iou : 0.f;
    top2 = (cmax >= 2) ? max_iou : 0.f;
  } else {
    float lo = FILT0;
    while (nci < 16 && nci < pos_cnt && lo > 0.f) {
      float hi = lo;
      lo = fmaxf(0.f, 1.f - 2.f * (1.f - lo));
      __syncthreads();
#pragma unroll 1
      for (int it = 0; it < NITER; ++it) {
        int v4i = it * P2T + tid;
        float4 o = ov4[v4i];
        float4 q = iu4[v4i];
        int j0 = v4i * 4;
        float ov_[4] = {o.x, o.y, o.z, o.w};
        float iu_[4] = {q.x, q.y, q.z, q.w};
#pragma unroll
        for (int c = 0; c < 4; ++c) {
          if (ov_[c] >= POS_T && iu_[c] > lo && iu_[c] <= hi) {
            int p = atomicAdd(&s_nci, 1);
            if (p < CAP) { ival[p] = iu_[c]; iidx[p] = j0 + c; }
          }
        }
      }
      __syncthreads();
      nci = min(s_nci, CAP);
    }
    if (tid == 0) { s_kth16 = 0.f; s_top2 = 0.f; }
    __syncthreads();
    for (int c = tid; c < nci; c += P2T) {
      float v = ival[c];
      int g = 0, e = 0;
      for (int x = 0; x < nci; ++x) {
        float w = ival[x];
        g += (w > v) ? 1 : 0;
        e += (w == v) ? 1 : 0;
      }
      if (g <= 15 && 15 < g + e) s_kth16 = v;
      if (g <= 1 && 1 < g + e) s_top2 = v;
    }
    __syncthreads();
    kth16 = s_kth16;
    top2 = s_top2;
  }
  const float t = (kth16 >= IOU_T) ? kth16 : IOU_T;

  {
    float lo = FILT0;
    while (ncs < 48 && lo > 0.f) {
      float hi = lo;
      lo = fmaxf(0.f, 1.f - 2.f * (1.f - lo));
      __syncthreads();
#pragma unroll 1
      for (int it = 0; it < NITER; ++it) {
        int v4i = it * P2T + tid;
        float4 o = ov4[v4i];
        int j0 = v4i * 4;
        float ov_[4] = {o.x, o.y, o.z, o.w};
#pragma unroll
        for (int c = 0; c < 4; ++c) {
          if (ov_[c] <= NEG_T) {
            float u = tf_uniform(k0, k1, ibase + (uint32_t)(j0 + c));
            if (u > lo && u <= hi) {
              int p = atomicAdd(&s_ncs, 1);
              if (p < CAP) { sval[p] = u; sidx[p] = j0 + c; }
            }
          }
        }
      }
      __syncthreads();
      ncs = min(s_ncs, CAP);
    }
  }
  if (tid == 0) s_kth48 = -INFINITY;
  __syncthreads();
  for (int c = tid; c < ncs; c += P2T) {
    float v = sval[c];
    int g = 0, e = 0;
    for (int x = 0; x < ncs; ++x) {
      float w = sval[x];
      g += (w > v) ? 1 : 0;
      e += (w == v) ? 1 : 0;
    }
    if (g <= 47 && 47 < g + e) s_kth48 = v;
  }
  __syncthreads();
  const float kth48 = s_kth48;
  for (int c = tid; c < ncs; c += P2T) {
    if (sval[c] >= kth48) atomicOr(&bitmap[sidx[c] >> 5], 1u << (sidx[c] & 31));
  }
  __syncthreads();

#pragma unroll 1
  for (int it = 0; it < NITER; ++it) {
    int v4i = it * P2T + tid;
    int j0 = v4i * 4;
    uint32_t w = bitmap[j0 >> 5];
    uint32_t sh = (uint32_t)(j0 & 31);
    float4 r;
    r.x = -1.f + (float)((w >> (sh + 0)) & 1u);
    r.y = -1.f + (float)((w >> (sh + 1)) & 1u);
    r.z = -1.f + (float)((w >> (sh + 2)) & 1u);
    r.w = -1.f + (float)((w >> (sh + 3)) & 1u);
    out4[v4i] = r;
  }
  __syncthreads();

  for (int c = tid; c < nci; c += P2T) {
    float v = ival[c];
    bool pos = (v >= t) || (h == 0 && v > top2);
    if (pos) {
      size_t gi = rowoff + (size_t)iidx[c];
      float nmv = nm[gi];
      if (nmv != 0.f) atomicAdd(&out[gi], 2.f * nmv);
    }
  }
}

// ---------------- mono fallback (round-1 kernel, validated) ----------------
__global__ __launch_bounds__(P2T) void label_kernel_mono(
    const float* __restrict__ ov, const float* __restrict__ iu,
    const float* __restrict__ nm, float* __restrict__ out,
    uint32_t K00, uint32_t K01, uint32_t K10, uint32_t K11,
    uint32_t K20, uint32_t K21) {
  const int bid = blockIdx.x;
  const int h = bid >> 6;
  const int b = bid & 63;
  const int tid = threadIdx.x;
  float POS_T, IOU_T; uint32_t k0, k1;
  row_consts(h, K00, K01, K10, K11, K20, K21, &POS_T, &IOU_T, &k0, &k1);
  const float NEG_T = 0.3f;
  const size_t rowoff = (size_t)b * ROWSTRIDE + (size_t)h * NROI;
  const float4* ov4 = (const float4*)(ov + rowoff);
  const float4* iu4 = (const float4*)(iu + rowoff);
  float4* out4 = (float4*)(out + rowoff);
  const uint32_t ibase = (uint32_t)b * (uint32_t)NROI;

  __shared__ float ival[CAP];
  __shared__ int   iidx[CAP];
  __shared__ float sval[CAP];
  __shared__ int   sidx[CAP];
  __shared__ uint32_t bitmap[NROI / 32];
  __shared__ int s_nci, s_ncs, s_poscnt;
  __shared__ uint32_t s_maxbits;
  __shared__ float s_kth16, s_top2, s_kth48;

  if (tid == 0) { s_nci = 0; s_ncs = 0; s_poscnt = 0; s_maxbits = 0u; }
  for (int w = tid; w < NROI / 32; w += P2T) bitmap[w] = 0u;
  __syncthreads();

  int poscnt_l = 0;
  uint32_t maxb_l = 0u;
#pragma unroll 1
  for (int it = 0; it < NITER; ++it) {
    int v4i = it * P2T + tid;
    float4 o = ov4[v4i];
    float4 q = iu4[v4i];
    int j0 = v4i * 4;
    float ov_[4] = {o.x, o.y, o.z, o.w};
    float iu_[4] = {q.x, q.y, q.z, q.w};
#pragma unroll
    for (int c = 0; c < 4; ++c) {
      float ovv = ov_[c], iuv = iu_[c];
      int j = j0 + c;
      bool pos = ovv >= POS_T;
      poscnt_l += pos ? 1 : 0;
      uint32_t ib = __float_as_uint(iuv);
      maxb_l = ib > maxb_l ? ib : maxb_l;
      if (pos && iuv > FILT0) {
        int p = atomicAdd(&s_nci, 1);
        if (p < CAP) { ival[p] = iuv; iidx[p] = j; }
      }
      if (ovv <= NEG_T) {
        float u = tf_uniform(k0, k1, ibase + (uint32_t)j);
        if (u > FILT0) {
          int p = atomicAdd(&s_ncs, 1);
          if (p < CAP) { sval[p] = u; sidx[p] = j; }
        }
      }
    }
  }
  atomicAdd(&s_poscnt, poscnt_l);
  atomicMax(&s_maxbits, maxb_l);
  __syncthreads();

  int nci = min(s_nci, CAP);
  int ncs = min(s_ncs, CAP);
  const int pos_cnt = s_poscnt;
  const float max_iou = __uint_as_float(s_maxbits);

  float kth16 = 0.f, top2 = 0.f;

  if (pos_cnt == 0) {
    if (tid == 0) s_nci = 0;
    __syncthreads();
#pragma unroll 1
    for (int it = 0; it < NITER; ++it) {
      int v4i = it * P2T + tid;
      float4 q = iu4[v4i];
      int j0 = v4i * 4;
      float iu_[4] = {q.x, q.y, q.z, q.w};
#pragma unroll
      for (int c = 0; c < 4; ++c) {
        if (__float_as_uint(iu_[c]) == s_maxbits) {
          int p = atomicAdd(&s_nci, 1);
          if (p < CAP) { ival[p] = iu_[c]; iidx[p] = j0 + c; }
        }
      }
    }
    __syncthreads();
    int cmax = s_nci;
    nci = min(cmax, CAP);
    kth16 = (cmax >= 16) ? max_iou : 0.f;
    top2 = (cmax >= 2) ? max_iou : 0.f;
  } else {
    float lo = FILT0;
    while (nci < 16 && nci < pos_cnt && lo > 0.f) {
      float hi = lo;
      lo = fmaxf(0.f, 1.f - 2.f * (1.f - lo));
      __syncthreads();
#pragma unroll 1
      for (int it = 0; it < NITER; ++it) {
        int v4i = it * P2T + tid;
        float4 o = ov4[v4i];
        float4 q = iu4[v4i];
        int j0 = v4i * 4;
        float ov_[4] = {o.x, o.y, o.z, o.w};
        float iu_[4] = {q.x, q.y, q.z, q.w};
#pragma unroll
        for (int c = 0; c < 4; ++c) {
          if (ov_[c] >= POS_T && iu_[c] > lo && iu_[c] <= hi) {
            int p = atomicAdd(&s_nci, 1);
            if (p < CAP) { ival[p] = iu_[c]; iidx[p] = j0 + c; }
          }
        }
      }
      __syncthreads();
      nci = min(s_nci, CAP);
    }
    if (tid == 0) { s_kth16 = 0.f; s_top2 = 0.f; }
    __syncthreads();
    for (int c = tid; c < nci; c += P2T) {
      float v = ival[c];
      int g = 0, e = 0;
      for (int x = 0; x < nci; ++x) {
        float w = ival[x];
        g += (w > v) ? 1 : 0;
        e += (w == v) ? 1 : 0;
      }
      if (g <= 15 && 15 < g + e) s_kth16 = v;
      if (g <= 1 && 1 < g + e) s_top2 = v;
    }
    __syncthreads();
    kth16 = s_kth16;
    top2 = s_top2;
  }
  const float t = (kth16 >= IOU_T) ? kth16 : IOU_T;

  {
    float lo = FILT0;
    while (ncs < 48 && lo > 0.f) {
      float hi = lo;
      lo = fmaxf(0.f, 1.f - 2.f * (1.f - lo));
      __syncthreads();
#pragma unroll 1
      for (int it = 0; it < NITER; ++it) {
        int v4i = it * P2T + tid;
        float4 o = ov4[v4i];
        int j0 = v4i * 4;
        float ov_[4] = {o.x, o.y, o.z, o.w};
#pragma unroll
        for (int c = 0; c < 4; ++c) {
          if (ov_[c] <= NEG_T) {
            float u = tf_uniform(k0, k1, ibase + (uint32_t)(j0 + c));
            if (u > lo && u <= hi) {
              int p = atomicAdd(&s_ncs, 1);
              if (p < CAP) { sval[p] = u; sidx[p] = j0 + c; }
            }
          }
        }
      }
      __syncthreads();
      ncs = min(s_ncs, CAP);
    }
  }
  if (tid == 0) s_kth48 = -INFINITY;
  __syncthreads();
  for (int c = tid; c < ncs; c += P2T) {
    float v = sval[c];
    int g = 0, e = 0;
    for (int x = 0; x < ncs; ++x) {
      float w = sval[x];
      g += (w > v) ? 1 : 0;
      e += (w == v) ? 1 : 0;
    }
    if (g <= 47 && 47 < g + e) s_kth48 = v;
  }
  __syncthreads();
  const float kth48 = s_kth48;
  for (int c = tid; c < ncs; c += P2T) {
    if (sval[c] >= kth48) atomicOr(&bitmap[sidx[c] >> 5], 1u << (sidx[c] & 31));
  }
  __syncthreads();

#pragma unroll 1
  for (int it = 0; it < NITER; ++it) {
    int v4i = it * P2T + tid;
    int j0 = v4i * 4;
    uint32_t w = bitmap[j0 >> 5];
    uint32_t sh = (uint32_t)(j0 & 31);
    float4 r;
    r.x = -1.f + (float)((w >> (sh + 0)) & 1u);
    r.y = -1.f + (float)((w >> (sh + 1)) & 1u);
    r.z = -1.f + (float)((w >> (sh + 2)) & 1u);
    r.w = -1.f + (float)((w >> (sh + 3)) & 1u);
    out4[v4i] = r;
  }
  __syncthreads();

  for (int c = tid; c < nci; c += P2T) {
    float v = ival[c];
    bool pos = (v >= t) || (h == 0 && v > top2);
    if (pos) {
      size_t gi = rowoff + (size_t)iidx[c];
      float nmv = nm[gi];
      if (nmv != 0.f) atomicAdd(&out[gi], 2.f * nmv);
    }
  }
}

extern "C" void kernel_launch(void* const* d_in, const int* in_sizes, int n_in,
                              void* d_out, int out_size, void* d_ws, size_t ws_size,
                              hipStream_t stream) {
  const float* ov = (const float*)d_in[0];
  const float* iu = (const float*)d_in[1];
  const float* nm = (const float*)d_in[2];
  float* out = (float*)d_out;

  uint32_t ka[3], kb[3];
  for (uint32_t h = 0; h < 3; ++h) tf_pair_host(0u, 42u, 0u, h, &ka[h], &kb[h]);

  const int nslots = 192 * SEGS;  // 1536
  const size_t ctr_bytes = (size_t)nslots * 2 * sizeof(uint32_t);  // 12 KB, 8B-aligned
  int SEGCAP = 192;  // mean ~66 pos / ~49 neg per seg; >10 sigma headroom
  size_t need = ctr_bytes + 2ull * nslots * SEGCAP * sizeof(uint2);
  if (ws_size < need) {
    SEGCAP = (ws_size > ctr_bytes)
                 ? (int)((ws_size - ctr_bytes) / (2ull * nslots * sizeof(uint2)))
                 : 0;
  }

  if (SEGCAP >= 96) {
    uint32_t* ctr = (uint32_t*)d_ws;
    uint2* posbuf = (uint2*)((char*)d_ws + ctr_bytes);
    uint2* negbuf = posbuf + (size_t)nslots * SEGCAP;
    hipLaunchKernelGGL(phase1, dim3(nslots), dim3(P1T), 0, stream,
                       ov, iu, out, ctr, posbuf, negbuf, SEGCAP,
                       ka[0], kb[0], ka[1], kb[1], ka[2], kb[2]);
    hipLaunchKernelGGL(phase2, dim3(192), dim3(P2T), 0, stream,
                       ov, iu, nm, out, ctr, posbuf, negbuf, SEGCAP,
                       ka[0], kb[0], ka[1], kb[1], ka[2], kb[2]);
  } else {
    hipLaunchKernelGGL(label_kernel_mono, dim3(192), dim3(P2T), 0, stream,
                       ov, iu, nm, out, ka[0], kb[0], ka[1], kb[1], ka[2], kb[2]);
  }
}

// Round 6
// 189.877 us; speedup vs baseline: 1.1131x; 1.0598x over previous
//
#include <hip/hip_runtime.h>
#include <stdint.h>
#include <math.h>

// LabelCls cascade label assignment — grid-stride dense-threefry 2-phase (R6).
// Inputs (64, 3*65536) f32; cascade h = cols [h*65536,(h+1)*65536). row = h*64+b.
//
// R6 vs R5 (phase1 55us, VALUBusy 53%, Occ 47%): R5 showed compute+memory
// serialize (29us VALU + 24us mem = 55) and occupancy stuck at 47% — grid 1536
// with 8-blocks/CU capacity lets the dispatcher fill ~192 CUs and idle ~64.
// Fix: grid = 2048 blocks (exactly 8/CU capacity, placement-proof) grid-striding
// over 6144 (row,seg) units (SEGS=32, 3 units/block exactly, zero imbalance).
//
// Phase 2 (192 blocks x 1024): prefix 32 seg counts, gather ~900 cands, exact
// rank-select (ties == lax.top_k), sparse fixups (pos: -1+2*nm, neg: 0).
// Slow path = full row recompute on overflow/deficit. Mono fallback if ws tiny.
//
// RNG: JAX threefry2x32 partitionable mode (verified absmax 0, R1-R5):
//   keys[h]=TF((0,42),(0,h)); bits=x0^x1 of TF(key_h,(0, b*65536+col));
//   u = bitcast((bits>>9)|0x3f800000)-1.   u>0.98f <=> (bits>>9)>8220836.

#define NROI 65536
#define ROWSTRIDE (3 * 65536)
#define SEGS 32
#define SEGLEN 2048
#define NUNITS (192 * SEGS)  // 6144
#define GRID1 2048
#define P1T 256
#define P1ITER 2   // SEGLEN/4/P1T
#define P2T 1024
#define CAP 2048
#define FILT0 0.98f
#define MTHR 8220836u
#define NITER 16  // slow/mono: 65536/4/1024

typedef float fvec4 __attribute__((ext_vector_type(4)));

// ---------------- threefry2x32 (20 rounds) ----------------
#define TF_ROUNDS(x0, x1, R0, R1, R2, R3)                         \
  x0 += x1; x1 = (x1 << R0) | (x1 >> (32 - R0)); x1 ^= x0;        \
  x0 += x1; x1 = (x1 << R1) | (x1 >> (32 - R1)); x1 ^= x0;        \
  x0 += x1; x1 = (x1 << R2) | (x1 >> (32 - R2)); x1 ^= x0;        \
  x0 += x1; x1 = (x1 << R3) | (x1 >> (32 - R3)); x1 ^= x0;

#define TF_BODY(k0, k1, k2, x0, x1)                               \
  TF_ROUNDS(x0, x1, 13, 15, 26, 6)  x0 += k1; x1 += k2 + 1u;      \
  TF_ROUNDS(x0, x1, 17, 29, 16, 24) x0 += k2; x1 += k0 + 2u;      \
  TF_ROUNDS(x0, x1, 13, 15, 26, 6)  x0 += k0; x1 += k1 + 3u;      \
  TF_ROUNDS(x0, x1, 17, 29, 16, 24) x0 += k1; x1 += k2 + 4u;      \
  TF_ROUNDS(x0, x1, 13, 15, 26, 6)  x0 += k2; x1 += k0 + 5u;

__device__ __forceinline__ float tf_uniform(uint32_t k0, uint32_t k1, uint32_t idx) {
  uint32_t k2 = k0 ^ k1 ^ 0x1BD11BDAu;
  uint32_t x0 = 0u + k0;
  uint32_t x1 = idx + k1;
  TF_BODY(k0, k1, k2, x0, x1)
  uint32_t bits = x0 ^ x1;
  return __uint_as_float((bits >> 9) | 0x3f800000u) - 1.0f;
}

// 4 independent threefry chains (ILP-4) for counters cbase..cbase+3.
__device__ __forceinline__ void tf4(uint32_t k0, uint32_t k1, uint32_t cbase,
                                    uint32_t m[4]) {
  uint32_t k2 = k0 ^ k1 ^ 0x1BD11BDAu;
  uint32_t x0[4], x1[4];
#pragma unroll
  for (int i = 0; i < 4; ++i) { x0[i] = k0; x1[i] = cbase + (uint32_t)i + k1; }
#define R4(r)                                                       \
  _Pragma("unroll") for (int i = 0; i < 4; ++i) {                   \
    x0[i] += x1[i];                                                 \
    x1[i] = (x1[i] << (r)) | (x1[i] >> (32 - (r)));                 \
    x1[i] ^= x0[i];                                                 \
  }
#define INJ4(a, bv, ridx)                                           \
  _Pragma("unroll") for (int i = 0; i < 4; ++i) {                   \
    x0[i] += (a); x1[i] += (bv) + (uint32_t)(ridx);                 \
  }
  R4(13) R4(15) R4(26) R4(6)  INJ4(k1, k2, 1)
  R4(17) R4(29) R4(16) R4(24) INJ4(k2, k0, 2)
  R4(13) R4(15) R4(26) R4(6)  INJ4(k0, k1, 3)
  R4(17) R4(29) R4(16) R4(24) INJ4(k1, k2, 4)
  R4(13) R4(15) R4(26) R4(6)  INJ4(k2, k0, 5)
#undef R4
#undef INJ4
#pragma unroll
  for (int i = 0; i < 4; ++i) m[i] = x0[i] ^ x1[i];
}

static void tf_pair_host(uint32_t k0, uint32_t k1, uint32_t c0, uint32_t c1,
                         uint32_t* o0, uint32_t* o1) {
  uint32_t k2 = k0 ^ k1 ^ 0x1BD11BDAu;
  uint32_t x0 = c0 + k0, x1 = c1 + k1;
  TF_BODY(k0, k1, k2, x0, x1)
  *o0 = x0; *o1 = x1;
}

__device__ __forceinline__ void row_consts(int h, uint32_t K00, uint32_t K01,
                                           uint32_t K10, uint32_t K11,
                                           uint32_t K20, uint32_t K21,
                                           float* POS_T, float* IOU_T,
                                           uint32_t* k0, uint32_t* k1) {
  *POS_T = (h == 0) ? 0.6f : ((h == 1) ? 0.7f : 0.8f);
  *IOU_T = (h == 0) ? 0.2f : ((h == 1) ? 0.3f : 0.4f);
  *k0 = (h == 0) ? K00 : ((h == 1) ? K10 : K20);
  *k1 = (h == 0) ? K01 : ((h == 1) ? K11 : K21);
}

// ---------------- Phase 1 ----------------
// 2048 blocks x 256 thr; grid-stride over 6144 units (3/block exactly).
__global__ __launch_bounds__(P1T) void phase1(
    const float* __restrict__ ov, const float* __restrict__ iu,
    float* __restrict__ out, uint32_t* __restrict__ ctr,
    uint2* __restrict__ posbuf, uint2* __restrict__ negbuf, int SEGCAP,
    uint32_t K00, uint32_t K01, uint32_t K10, uint32_t K11,
    uint32_t K20, uint32_t K21) {
  const int tid = threadIdx.x;
  __shared__ int s_np, s_nn;
  if (tid == 0) { s_np = 0; s_nn = 0; }
  __syncthreads();

  const fvec4 m1 = {-1.f, -1.f, -1.f, -1.f};

  for (int u = blockIdx.x; u < NUNITS; u += GRID1) {
    const int row = u >> 5;  // SEGS = 32
    const int seg = u & 31;
    const int h = row >> 6;
    const int b = row & 63;
    float POS_T, IOU_T; uint32_t k0, k1;
    row_consts(h, K00, K01, K10, K11, K20, K21, &POS_T, &IOU_T, &k0, &k1);

    const size_t rowoff = (size_t)b * ROWSTRIDE + (size_t)h * NROI;
    const int segoff = seg * SEGLEN;
    const fvec4* o4 = (const fvec4*)(ov + rowoff + segoff);
    const fvec4* q4 = (const fvec4*)(iu + rowoff + segoff);
    fvec4* w4 = (fvec4*)(out + rowoff + segoff);
    const uint32_t cbase0 = (uint32_t)b * 65536u + (uint32_t)segoff;
    uint2* pb = posbuf + (size_t)u * SEGCAP;
    uint2* nb = negbuf + (size_t)u * SEGCAP;

#pragma unroll
    for (int it = 0; it < P1ITER; ++it) {
      int v = it * P1T + tid;
      fvec4 o = __builtin_nontemporal_load(&o4[v]);
      fvec4 q = __builtin_nontemporal_load(&q4[v]);
      __builtin_nontemporal_store(m1, &w4[v]);
      uint32_t m[4];
      tf4(k0, k1, cbase0 + (uint32_t)(4 * v), m);
      int j0 = segoff + 4 * v;  // row-local index
#pragma unroll
      for (int c = 0; c < 4; ++c) {
        float ovv = o[c], iuv = q[c];
        if (ovv >= POS_T && iuv > FILT0) {
          int p = atomicAdd(&s_np, 1);
          if (p < SEGCAP) pb[p] = make_uint2(__float_as_uint(iuv), (uint32_t)(j0 + c));
        }
        uint32_t r = m[c] >> 9;
        if (ovv <= 0.3f && r > MTHR) {
          float uu = __uint_as_float(r | 0x3f800000u) - 1.0f;
          int p = atomicAdd(&s_nn, 1);
          if (p < SEGCAP) nb[p] = make_uint2(__float_as_uint(uu), (uint32_t)(j0 + c));
        }
      }
    }
    __syncthreads();
    if (tid == 0) {
      ctr[u * 2 + 0] = (uint32_t)s_np;  // raw; phase2 checks > SEGCAP
      ctr[u * 2 + 1] = (uint32_t)s_nn;
      s_np = 0; s_nn = 0;
    }
    __syncthreads();
  }
}

// ---------------- Phase 2 ----------------
__global__ __launch_bounds__(P2T) void phase2(
    const float* __restrict__ ov, const float* __restrict__ iu,
    const float* __restrict__ nm, float* __restrict__ out,
    const uint32_t* __restrict__ ctr,
    const uint2* __restrict__ posbuf, const uint2* __restrict__ negbuf, int SEGCAP,
    uint32_t K00, uint32_t K01, uint32_t K10, uint32_t K11,
    uint32_t K20, uint32_t K21) {
  const int row = blockIdx.x;
  const int h = row >> 6;
  const int b = row & 63;
  const int tid = threadIdx.x;
  float POS_T, IOU_T; uint32_t k0, k1;
  row_consts(h, K00, K01, K10, K11, K20, K21, &POS_T, &IOU_T, &k0, &k1);
  const float NEG_T = 0.3f;
  const size_t rowoff = (size_t)b * ROWSTRIDE + (size_t)h * NROI;
  const uint32_t ibase = (uint32_t)b * 65536u;

  __shared__ float ival[CAP];
  __shared__ int   iidx[CAP];
  __shared__ float sval[CAP];
  __shared__ int   sidx[CAP];
  __shared__ uint32_t bitmap[NROI / 32];
  __shared__ int pcnt[SEGS], ncnt[SEGS], pbase[SEGS], nbase[SEGS];
  __shared__ int s_cp, s_cn, s_ok;
  __shared__ int s_nci, s_ncs, s_poscnt;
  __shared__ uint32_t s_maxbits;
  __shared__ float s_kth16, s_top2, s_kth48;

  if (tid < SEGS) {
    pcnt[tid] = (int)ctr[(row * SEGS + tid) * 2 + 0];
    ncnt[tid] = (int)ctr[(row * SEGS + tid) * 2 + 1];
  }
  __syncthreads();
  if (tid == 0) {
    int a = 0, c2 = 0, ok = 1;
    for (int s = 0; s < SEGS; ++s) {
      if (pcnt[s] > SEGCAP || ncnt[s] > SEGCAP) ok = 0;
      pbase[s] = a; a += pcnt[s];
      nbase[s] = c2; c2 += ncnt[s];
    }
    if (a < 16 || a > CAP || c2 < 48 || c2 > CAP) ok = 0;
    s_cp = a; s_cn = c2; s_ok = ok;
  }
  __syncthreads();

  if (s_ok) {
    const int cp = s_cp, cn = s_cn;
    // gather: one wave per seg chunk; 1024 threads over 32 segs
    for (int s = tid >> 5; s < SEGS; s += 32) {  // 32 groups of 32 threads
      int lane = tid & 31;
      int n = pcnt[s], bb = pbase[s];
      const uint2* src = posbuf + (size_t)(row * SEGS + s) * SEGCAP;
      for (int i = lane; i < n; i += 32) {
        uint2 e = src[i];
        ival[bb + i] = __uint_as_float(e.x);
        iidx[bb + i] = (int)e.y;
      }
      n = ncnt[s]; bb = nbase[s];
      const uint2* src2 = negbuf + (size_t)(row * SEGS + s) * SEGCAP;
      for (int i = lane; i < n; i += 32) {
        uint2 e = src2[i];
        sval[bb + i] = __uint_as_float(e.x);
        sidx[bb + i] = (int)e.y;
      }
    }
    if (tid == 0) { s_kth16 = 0.f; s_top2 = 0.f; s_kth48 = -INFINITY; }
    __syncthreads();
    for (int c = tid; c < cp; c += P2T) {
      float v = ival[c];
      int g = 0, e = 0;
      for (int x = 0; x < cp; ++x) {
        float w = ival[x];
        g += (w > v) ? 1 : 0;
        e += (w == v) ? 1 : 0;
      }
      if (g <= 15 && 15 < g + e) s_kth16 = v;
      if (g <= 1 && 1 < g + e) s_top2 = v;
    }
    for (int c = tid; c < cn; c += P2T) {
      float v = sval[c];
      int g = 0, e = 0;
      for (int x = 0; x < cn; ++x) {
        float w = sval[x];
        g += (w > v) ? 1 : 0;
        e += (w == v) ? 1 : 0;
      }
      if (g <= 47 && 47 < g + e) s_kth48 = v;
    }
    __syncthreads();
    const float t = (s_kth16 >= IOU_T) ? s_kth16 : IOU_T;  // cp>=16 -> kth16>0.98
    const float top2 = s_top2;
    const float kth48 = s_kth48;
    for (int c = tid; c < cp; c += P2T) {
      float v = ival[c];
      bool pos = (v >= t) || (h == 0 && v > top2);
      if (pos) {
        size_t gi = rowoff + (size_t)iidx[c];
        out[gi] = -1.f + 2.f * nm[gi];  // neg impossible here (ov>=POS_T>0.3)
      }
    }
    for (int c = tid; c < cn; c += P2T) {
      if (sval[c] >= kth48) out[rowoff + (size_t)sidx[c]] = 0.f;  // -1 + 1
    }
    return;
  }

  // ---------- slow path: full row recompute (validated round-1 logic) ----------
  const float4* ov4 = (const float4*)(ov + rowoff);
  const float4* iu4 = (const float4*)(iu + rowoff);
  float4* out4 = (float4*)(out + rowoff);

  if (tid == 0) { s_nci = 0; s_ncs = 0; s_poscnt = 0; s_maxbits = 0u; }
  for (int w = tid; w < NROI / 32; w += P2T) bitmap[w] = 0u;
  __syncthreads();

  int poscnt_l = 0;
  uint32_t maxb_l = 0u;
#pragma unroll 1
  for (int it = 0; it < NITER; ++it) {
    int v4i = it * P2T + tid;
    float4 o = ov4[v4i];
    float4 q = iu4[v4i];
    int j0 = v4i * 4;
    float ov_[4] = {o.x, o.y, o.z, o.w};
    float iu_[4] = {q.x, q.y, q.z, q.w};
#pragma unroll
    for (int c = 0; c < 4; ++c) {
      float ovv = ov_[c], iuv = iu_[c];
      int j = j0 + c;
      bool pos = ovv >= POS_T;
      poscnt_l += pos ? 1 : 0;
      uint32_t ib = __float_as_uint(iuv);
      maxb_l = ib > maxb_l ? ib : maxb_l;
      if (pos && iuv > FILT0) {
        int p = atomicAdd(&s_nci, 1);
        if (p < CAP) { ival[p] = iuv; iidx[p] = j; }
      }
      if (ovv <= NEG_T) {
        float u = tf_uniform(k0, k1, ibase + (uint32_t)j);
        if (u > FILT0) {
          int p = atomicAdd(&s_ncs, 1);
          if (p < CAP) { sval[p] = u; sidx[p] = j; }
        }
      }
    }
  }
  atomicAdd(&s_poscnt, poscnt_l);
  atomicMax(&s_maxbits, maxb_l);
  __syncthreads();

  int nci = min(s_nci, CAP);
  int ncs = min(s_ncs, CAP);
  const int pos_cnt = s_poscnt;
  const float max_iou = __uint_as_float(s_maxbits);

  float kth16 = 0.f, top2 = 0.f;

  if (pos_cnt == 0) {
    if (tid == 0) s_nci = 0;
    __syncthreads();
#pragma unroll 1
    for (int it = 0; it < NITER; ++it) {
      int v4i = it * P2T + tid;
      float4 q = iu4[v4i];
      int j0 = v4i * 4;
      float iu_[4] = {q.x, q.y, q.z, q.w};
#pragma unroll
      for (int c = 0; c < 4; ++c) {
        if (__float_as_uint(iu_[c]) == s_maxbits) {
          int p = atomicAdd(&s_nci, 1);
          if (p < CAP) { ival[p] = iu_[c]; iidx[p] = j0 + c; }
        }
      }
    }
    __syncthreads();
    int cmax = s_nci;
    nci = min(cmax, CAP);
    kth16 = (cmax >= 16) ? max_iou : 0.f;
    top2 = (cmax >= 2) ? max_iou : 0.f;
  } else {
    float lo = FILT0;
    while (nci < 16 && nci < pos_cnt && lo > 0.f) {
      float hi = lo;
      lo = fmaxf(0.f, 1.f - 2.f * (1.f - lo));
      __syncthreads();
#pragma unroll 1
      for (int it = 0; it < NITER; ++it) {
        int v4i = it * P2T + tid;
        float4 o = ov4[v4i];
        float4 q = iu4[v4i];
        int j0 = v4i * 4;
        float ov_[4] = {o.x, o.y, o.z, o.w};
        float iu_[4] = {q.x, q.y, q.z, q.w};
#pragma unroll
        for (int c = 0; c < 4; ++c) {
          if (ov_[c] >= POS_T && iu_[c] > lo && iu_[c] <= hi) {
            int p = atomicAdd(&s_nci, 1);
            if (p < CAP) { ival[p] = iu_[c]; iidx[p] = j0 + c; }
          }
        }
      }
      __syncthreads();
      nci = min(s_nci, CAP);
    }
    if (tid == 0) { s_kth16 = 0.f; s_top2 = 0.f; }
    __syncthreads();
    for (int c = tid; c < nci; c += P2T) {
      float v = ival[c];
      int g = 0, e = 0;
      for (int x = 0; x < nci; ++x) {
        float w = ival[x];
        g += (w > v) ? 1 : 0;
        e += (w == v) ? 1 : 0;
      }
      if (g <= 15 && 15 < g + e) s_kth16 = v;
      if (g <= 1 && 1 < g + e) s_top2 = v;
    }
    __syncthreads();
    kth16 = s_kth16;
    top2 = s_top2;
  }
  const float t = (kth16 >= IOU_T) ? kth16 : IOU_T;

  {
    float lo = FILT0;
    while (ncs < 48 && lo > 0.f) {
      float hi = lo;
      lo = fmaxf(0.f, 1.f - 2.f * (1.f - lo));
      __syncthreads();
#pragma unroll 1
      for (int it = 0; it < NITER; ++it) {
        int v4i = it * P2T + tid;
        float4 o = ov4[v4i];
        int j0 = v4i * 4;
        float ov_[4] = {o.x, o.y, o.z, o.w};
#pragma unroll
        for (int c = 0; c < 4; ++c) {
          if (ov_[c] <= NEG_T) {
            float u = tf_uniform(k0, k1, ibase + (uint32_t)(j0 + c));
            if (u > lo && u <= hi) {
              int p = atomicAdd(&s_ncs, 1);
              if (p < CAP) { sval[p] = u; sidx[p] = j0 + c; }
            }
          }
        }
      }
      __syncthreads();
      ncs = min(s_ncs, CAP);
    }
  }
  if (tid == 0) s_kth48 = -INFINITY;
  __syncthreads();
  for (int c = tid; c < ncs; c += P2T) {
    float v = sval[c];
    int g = 0, e = 0;
    for (int x = 0; x < ncs; ++x) {
      float w = sval[x];
      g += (w > v) ? 1 : 0;
      e += (w == v) ? 1 : 0;
    }
    if (g <= 47 && 47 < g + e) s_kth48 = v;
  }
  __syncthreads();
  const float kth48 = s_kth48;
  for (int c = tid; c < ncs; c += P2T) {
    if (sval[c] >= kth48) atomicOr(&bitmap[sidx[c] >> 5], 1u << (sidx[c] & 31));
  }
  __syncthreads();

#pragma unroll 1
  for (int it = 0; it < NITER; ++it) {
    int v4i = it * P2T + tid;
    int j0 = v4i * 4;
    uint32_t w = bitmap[j0 >> 5];
    uint32_t sh = (uint32_t)(j0 & 31);
    float4 r;
    r.x = -1.f + (float)((w >> (sh + 0)) & 1u);
    r.y = -1.f + (float)((w >> (sh + 1)) & 1u);
    r.z = -1.f + (float)((w >> (sh + 2)) & 1u);
    r.w = -1.f + (float)((w >> (sh + 3)) & 1u);
    out4[v4i] = r;
  }
  __syncthreads();

  for (int c = tid; c < nci; c += P2T) {
    float v = ival[c];
    bool pos = (v >= t) || (h == 0 && v > top2);
    if (pos) {
      size_t gi = rowoff + (size_t)iidx[c];
      float nmv = nm[gi];
      if (nmv != 0.f) atomicAdd(&out[gi], 2.f * nmv);
    }
  }
}

// ---------------- mono fallback (round-1 kernel, validated) ----------------
__global__ __launch_bounds__(P2T) void label_kernel_mono(
    const float* __restrict__ ov, const float* __restrict__ iu,
    const float* __restrict__ nm, float* __restrict__ out,
    uint32_t K00, uint32_t K01, uint32_t K10, uint32_t K11,
    uint32_t K20, uint32_t K21) {
  const int bid = blockIdx.x;
  const int h = bid >> 6;
  const int b = bid & 63;
  const int tid = threadIdx.x;
  float POS_T, IOU_T; uint32_t k0, k1;
  row_consts(h, K00, K01, K10, K11, K20, K21, &POS_T, &IOU_T, &k0, &k1);
  const float NEG_T = 0.3f;
  const size_t rowoff = (size_t)b * ROWSTRIDE + (size_t)h * NROI;
  const float4* ov4 = (const float4*)(ov + rowoff);
  const float4* iu4 = (const float4*)(iu + rowoff);
  float4* out4 = (float4*)(out + rowoff);
  const uint32_t ibase = (uint32_t)b * (uint32_t)NROI;

  __shared__ float ival[CAP];
  __shared__ int   iidx[CAP];
  __shared__ float sval[CAP];
  __shared__ int   sidx[CAP];
  __shared__ uint32_t bitmap[NROI / 32];
  __shared__ int s_nci, s_ncs, s_poscnt;
  __shared__ uint32_t s_maxbits;
  __shared__ float s_kth16, s_top2, s_kth48;

  if (tid == 0) { s_nci = 0; s_ncs = 0; s_poscnt = 0; s_maxbits = 0u; }
  for (int w = tid; w < NROI / 32; w += P2T) bitmap[w] = 0u;
  __syncthreads();

  int poscnt_l = 0;
  uint32_t maxb_l = 0u;
#pragma unroll 1
  for (int it = 0; it < NITER; ++it) {
    int v4i = it * P2T + tid;
    float4 o = ov4[v4i];
    float4 q = iu4[v4i];
    int j0 = v4i * 4;
    float ov_[4] = {o.x, o.y, o.z, o.w};
    float iu_[4] = {q.x, q.y, q.z, q.w};
#pragma unroll
    for (int c = 0; c < 4; ++c) {
      float ovv = ov_[c], iuv = iu_[c];
      int j = j0 + c;
      bool pos = ovv >= POS_T;
      poscnt_l += pos ? 1 : 0;
      uint32_t ib = __float_as_uint(iuv);
      maxb_l = ib > maxb_l ? ib : maxb_l;
      if (pos && iuv > FILT0) {
        int p = atomicAdd(&s_nci, 1);
        if (p < CAP) { ival[p] = iuv; iidx[p] = j; }
      }
      if (ovv <= NEG_T) {
        float u = tf_uniform(k0, k1, ibase + (uint32_t)j);
        if (u > FILT0) {
          int p = atomicAdd(&s_ncs, 1);
          if (p < CAP) { sval[p] = u; sidx[p] = j; }
        }
      }
    }
  }
  atomicAdd(&s_poscnt, poscnt_l);
  atomicMax(&s_maxbits, maxb_l);
  __syncthreads();

  int nci = min(s_nci, CAP);
  int ncs = min(s_ncs, CAP);
  const int pos_cnt = s_poscnt;
  const float max_iou = __uint_as_float(s_maxbits);

  float kth16 = 0.f, top2 = 0.f;

  if (pos_cnt == 0) {
    if (tid == 0) s_nci = 0;
    __syncthreads();
#pragma unroll 1
    for (int it = 0; it < NITER; ++it) {
      int v4i = it * P2T + tid;
      float4 q = iu4[v4i];
      int j0 = v4i * 4;
      float iu_[4] = {q.x, q.y, q.z, q.w};
#pragma unroll
      for (int c = 0; c < 4; ++c) {
        if (__float_as_uint(iu_[c]) == s_maxbits) {
          int p = atomicAdd(&s_nci, 1);
          if (p < CAP) { ival[p] = iu_[c]; iidx[p] = j0 + c; }
        }
      }
    }
    __syncthreads();
    int cmax = s_nci;
    nci = min(cmax, CAP);
    kth16 = (cmax >= 16) ? max_iou : 0.f;
    top2 = (cmax >= 2) ? max_iou : 0.f;
  } else {
    float lo = FILT0;
    while (nci < 16 && nci < pos_cnt && lo > 0.f) {
      float hi = lo;
      lo = fmaxf(0.f, 1.f - 2.f * (1.f - lo));
      __syncthreads();
#pragma unroll 1
      for (int it = 0; it < NITER; ++it) {
        int v4i = it * P2T + tid;
        float4 o = ov4[v4i];
        float4 q = iu4[v4i];
        int j0 = v4i * 4;
        float ov_[4] = {o.x, o.y, o.z, o.w};
        float iu_[4] = {q.x, q.y, q.z, q.w};
#pragma unroll
        for (int c = 0; c < 4; ++c) {
          if (ov_[c] >= POS_T && iu_[c] > lo && iu_[c] <= hi) {
            int p = atomicAdd(&s_nci, 1);
            if (p < CAP) { ival[p] = iu_[c]; iidx[p] = j0 + c; }
          }
        }
      }
      __syncthreads();
      nci = min(s_nci, CAP);
    }
    if (tid == 0) { s_kth16 = 0.f; s_top2 = 0.f; }
    __syncthreads();
    for (int c = tid; c < nci; c += P2T) {
      float v = ival[c];
      int g = 0, e = 0;
      for (int x = 0; x < nci; ++x) {
        float w = ival[x];
        g += (w > v) ? 1 : 0;
        e += (w == v) ? 1 : 0;
      }
      if (g <= 15 && 15 < g + e) s_kth16 = v;
      if (g <= 1 && 1 < g + e) s_top2 = v;
    }
    __syncthreads();
    kth16 = s_kth16;
    top2 = s_top2;
  }
  const float t = (kth16 >= IOU_T) ? kth16 : IOU_T;

  {
    float lo = FILT0;
    while (ncs < 48 && lo > 0.f) {
      float hi = lo;
      lo = fmaxf(0.f, 1.f - 2.f * (1.f - lo));
      __syncthreads();
#pragma unroll 1
      for (int it = 0; it < NITER; ++it) {
        int v4i = it * P2T + tid;
        float4 o = ov4[v4i];
        int j0 = v4i * 4;
        float ov_[4] = {o.x, o.y, o.z, o.w};
#pragma unroll
        for (int c = 0; c < 4; ++c) {
          if (ov_[c] <= NEG_T) {
            float u = tf_uniform(k0, k1, ibase + (uint32_t)(j0 + c));
            if (u > lo && u <= hi) {
              int p = atomicAdd(&s_ncs, 1);
              if (p < CAP) { sval[p] = u; sidx[p] = j0 + c; }
            }
          }
        }
      }
      __syncthreads();
      ncs = min(s_ncs, CAP);
    }
  }
  if (tid == 0) s_kth48 = -INFINITY;
  __syncthreads();
  for (int c = tid; c < ncs; c += P2T) {
    float v = sval[c];
    int g = 0, e = 0;
    for (int x = 0; x < ncs; ++x) {
      float w = sval[x];
      g += (w > v) ? 1 : 0;
      e += (w == v) ? 1 : 0;
    }
    if (g <= 47 && 47 < g + e) s_kth48 = v;
  }
  __syncthreads();
  const float kth48 = s_kth48;
  for (int c = tid; c < ncs; c += P2T) {
    if (sval[c] >= kth48) atomicOr(&bitmap[sidx[c] >> 5], 1u << (sidx[c] & 31));
  }
  __syncthreads();

#pragma unroll 1
  for (int it = 0; it < NITER; ++it) {
    int v4i = it * P2T + tid;
    int j0 = v4i * 4;
    uint32_t w = bitmap[j0 >> 5];
    uint32_t sh = (uint32_t)(j0 & 31);
    float4 r;
    r.x = -1.f + (float)((w >> (sh + 0)) & 1u);
    r.y = -1.f + (float)((w >> (sh + 1)) & 1u);
    r.z = -1.f + (float)((w >> (sh + 2)) & 1u);
    r.w = -1.f + (float)((w >> (sh + 3)) & 1u);
    out4[v4i] = r;
  }
  __syncthreads();

  for (int c = tid; c < nci; c += P2T) {
    float v = ival[c];
    bool pos = (v >= t) || (h == 0 && v > top2);
    if (pos) {
      size_t gi = rowoff + (size_t)iidx[c];
      float nmv = nm[gi];
      if (nmv != 0.f) atomicAdd(&out[gi], 2.f * nmv);
    }
  }
}

extern "C" void kernel_launch(void* const* d_in, const int* in_sizes, int n_in,
                              void* d_out, int out_size, void* d_ws, size_t ws_size,
                              hipStream_t stream) {
  const float* ov = (const float*)d_in[0];
  const float* iu = (const float*)d_in[1];
  const float* nm = (const float*)d_in[2];
  float* out = (float*)d_out;

  uint32_t ka[3], kb[3];
  for (uint32_t h = 0; h < 3; ++h) tf_pair_host(0u, 42u, 0u, h, &ka[h], &kb[h]);

  const size_t ctr_bytes = (size_t)NUNITS * 2 * sizeof(uint32_t);  // 48 KB, 8B-aligned
  int SEGCAP = 96;  // mean ~16 pos / ~12 neg per 2048-elem unit; >15 sigma headroom
  size_t need = ctr_bytes + 2ull * NUNITS * SEGCAP * sizeof(uint2);
  if (ws_size < need) {
    SEGCAP = (ws_size > ctr_bytes)
                 ? (int)((ws_size - ctr_bytes) / (2ull * NUNITS * sizeof(uint2)))
                 : 0;
  }

  if (SEGCAP >= 48) {
    uint32_t* ctr = (uint32_t*)d_ws;
    uint2* posbuf = (uint2*)((char*)d_ws + ctr_bytes);
    uint2* negbuf = posbuf + (size_t)NUNITS * SEGCAP;
    hipLaunchKernelGGL(phase1, dim3(GRID1), dim3(P1T), 0, stream,
                       ov, iu, out, ctr, posbuf, negbuf, SEGCAP,
                       ka[0], kb[0], ka[1], kb[1], ka[2], kb[2]);
    hipLaunchKernelGGL(phase2, dim3(192), dim3(P2T), 0, stream,
                       ov, iu, nm, out, ctr, posbuf, negbuf, SEGCAP,
                       ka[0], kb[0], ka[1], kb[1], ka[2], kb[2]);
  } else {
    hipLaunchKernelGGL(label_kernel_mono, dim3(192), dim3(P2T), 0, stream,
                       ov, iu, nm, out, ka[0], kb[0], ka[1], kb[1], ka[2], kb[2]);
  }
}